// Round 7
// baseline (239.291 us; speedup 1.0000x reference)
//
#include <hip/hip_runtime.h>
#include <stdint.h>

typedef unsigned short u16;
using short8 = __attribute__((ext_vector_type(8))) short;
using f32x4  = __attribute__((ext_vector_type(4))) float;

#define NB 4
#define NN 128
#define NF 32
#define ND 64

// ---- workspace byte offsets ----
#define OFF_A     0u
#define OFF_ACC   262144u
#define OFF_AAT   262400u
#define OFF_RA    524544u
#define OFF_W     526592u
#define OFF_RM    1116416u
#define OFF_CM    1247488u
#define OFF_RX    1378560u
#define OFF_CX    1509632u
#define OFF_BF    1640960u
#define OFF_ATB   1641472u
#define OFF_WB    1772544u
#define OFF_X2    1936384u
#define OFF_XC    10324992u
#define OFF_CA    10357760u
#define OFF_UA    18713600u
#define OFF_UB    27102208u
#define OFF_UC    35490816u
#define OFF_UD    43879424u
#define OFF_YACC  52268032u

__device__ __forceinline__ float b2f(u16 v){
  union { uint32_t u; float f; } x; x.u = ((uint32_t)v) << 16; return x.f;
}
__device__ __forceinline__ u16 f2b(float f){
  union { uint32_t u; float f2; } x; x.f2 = f;
  uint32_t u = x.u;
  return (u16)((u + 0x7FFFu + ((u >> 16) & 1u)) >> 16);
}

#define MFMA16(a,b,c) __builtin_amdgcn_mfma_f32_16x16x32_bf16((a),(b),(c),0,0,0)

__device__ __constant__ signed char dR1[18] = {0,9,1,10,2,3,4,13,14,19,5,7,15,18,6,8,16,17};
__device__ __constant__ signed char dR2[18] = {-1,11,-1,12,-1,-1,-1,-1,-1,-1,-1,-1,-1,-1,-1,-1,-1,-1};

// ---- fused setup: scatter+bias | xc (bf16 copy of x) | build W ; inline dtype detect ----
__global__ void k_setup(const int* __restrict__ ei, const int* __restrict__ bat,
                        const void* __restrict__ ews, float* __restrict__ A, int E,
                        const void* __restrict__ xs, u16* __restrict__ xc,
                        const void* __restrict__ c1s, const void* __restrict__ c2s,
                        const void* __restrict__ b1s, const void* __restrict__ b2s,
                        float* __restrict__ W, u16* __restrict__ Wb,
                        float* __restrict__ bfv)
{
  __shared__ int flg;
  const u16* x16 = (const u16*)xs;
  if (threadIdx.x == 0) flg = 0;
  __syncthreads();
  int hit = 0;
  for (int k = threadIdx.x; k < 1024; k += 256){
    u16 u = x16[k];
    if (((u >> 7) & 0xFF) >= 0x90) hit = 1;
  }
  if (hit) flg = 1;
  __syncthreads();
  const int isf = flg;

  const int bx = blockIdx.x;
  if (bx < 32){
    if (bx == 0 && threadIdx.x < 128){
      int tt = threadIdx.x;
      const void* bsrc = (tt < 64) ? b1s : b2s;
      int idx = tt & 63;
      bfv[tt] = isf ? ((const float*)bsrc)[idx] : b2f(((const u16*)bsrc)[idx]);
    }
    for (int t = bx*256 + threadIdx.x; t < E; t += 32*256){
      int s = ei[t], dnode = ei[E + t];
      int g = bat[s];
      int r = s - g*NN, c = dnode - g*NN;
      float wv = isf ? ((const float*)ews)[t] : b2f(((const u16*)ews)[t]);
      atomicAdd(&A[(g*NN + r)*NN + c], wv);
    }
  } else if (bx < 40){
    int idx8 = ((bx - 32)*256 + threadIdx.x)*8;
    if (!isf){
      *(short8*)(xc + idx8) = *(const short8*)(x16 + idx8);
    } else {
      const float* xfp = (const float*)xs;
      short8 v;
      #pragma unroll
      for (int k = 0; k < 8; k++) v[k] = (short)f2b(xfp[idx8 + k]);
      *(short8*)(xc + idx8) = v;
    }
  } else {
    int gl = (bx - 40)*256 + threadIdx.x;
    if (gl >= 2*1152*64) return;
    int L = gl / (1152*64);
    int rem = gl - L*1152*64;
    int row = rem >> 6, e = rem & 63;
    int slot = row >> 6, d = row & 63;
    const void* cr = L ? c2s : c1s;
    int base = (d*64 + e)*20;
    int i1 = base + dR1[slot];
    float v = isf ? ((const float*)cr)[i1] : b2f(((const u16*)cr)[i1]);
    if (dR2[slot] >= 0){
      int i2 = base + dR2[slot];
      v += isf ? ((const float*)cr)[i2] : b2f(((const u16*)cr)[i2]);
    }
    float scale = (slot == 9) ? 1.0f : (1.0f/128.0f);
    v *= scale;
    W[gl] = v;
    if (slot < 10)
      Wb[(((size_t)L*10 + slot)*64 + e)*64 + d] = f2b(v);
  }
}

// ---- fused A-processing, XCD-pair aligned: b = (bid&7)>>1, iq = 2*(bid>>3)+(bid&1) ----
__global__ __launch_bounds__(256) void k_prepA(const float* __restrict__ A, float* __restrict__ AAt,
                                               u16* __restrict__ ATb, float* __restrict__ rA,
                                               float* __restrict__ cA){
  const int bid = blockIdx.x;
  const int xcd = bid & 7;
  const int b = xcd >> 1;
  const int iq = 2*(bid >> 3) + (xcd & 1);
  if (iq >= 33) return;
  const int t = threadIdx.x;
  if (iq < 32){
    int j = t & 127, ih = t >> 7;
    int i0 = iq*4 + ih, i1 = i0 + 2;
    const float* Ab = A + b*NN*NN;
    float acc0 = 0.f, acc1 = 0.f;
    #pragma unroll 4
    for (int k = 0; k < 128; k += 4){
      float4 aj = *(const float4*)(Ab + j*128 + k);
      float4 a0 = *(const float4*)(Ab + i0*128 + k);
      float4 a1 = *(const float4*)(Ab + i1*128 + k);
      acc0 += a0.x*aj.x + a0.y*aj.y + a0.z*aj.z + a0.w*aj.w;
      acc1 += a1.x*aj.x + a1.y*aj.y + a1.z*aj.z + a1.w*aj.w;
    }
    AAt[(b*NN + i0)*NN + j] = acc0;
    AAt[(b*NN + i1)*NN + j] = acc1;
  } else {
    __shared__ float lds[128][129];
    for (int l = 0; l < 64; l++){
      int idx = l*256 + t;
      lds[idx >> 7][idx & 127] = A[b*16384 + idx];
    }
    __syncthreads();
    for (int l = 0; l < 64; l++){
      int idx = l*256 + t;
      int r = idx >> 7, c = idx & 127;
      ATb[b*16384 + idx] = f2b(lds[c][r]);
    }
    if (t < 128){
      float s = 0.f;
      for (int j = 0; j < 128; j++) s += lds[t][j];
      rA[b*NN + t] = s;
    } else {
      int c = t - 128;
      float s = 0.f;
      for (int j = 0; j < 128; j++) s += lds[j][c];
      cA[b*NN + c] = s;
    }
  }
}

#define SJ32 70   // u32 stride, bf16-pair staging
#define SJF  67   // fp32 stride, Yacc staging
#define SXE  34   // u32 stride, X pair-packed transpose staging

// ---- fused mix/rowcol, XCD-pair aligned: b = (bid&7)>>1, sub = 2*(bid>>3)+(bid&1) ----
__global__ __launch_bounds__(256) void k_mixrow(const u16* __restrict__ Xs, const float* __restrict__ A,
    const float* __restrict__ AAt, const float* __restrict__ rA, const float* __restrict__ cA,
    const u16* __restrict__ xc, const u16* __restrict__ Wb,
    u16* __restrict__ Ua, u16* __restrict__ Ub, u16* __restrict__ Uc, u16* __restrict__ Ud,
    float* __restrict__ Yacc,
    float* __restrict__ RM, float* __restrict__ CM,
    float* __restrict__ RX, float* __restrict__ CXv, int first)
{
  const int bid = blockIdx.x;
  const int xcd = bid & 7;
  const int b = xcd >> 1;
  const int sub = 2*(bid >> 3) + (xcd & 1);   // 0..319
  const int t = threadIdx.x;

  if (sub >= 256){
    const int d = sub - 256;                  // 0..63
    if (first){
      if (t < 128){
        const int i = t;
        if (d < NF){
          float xv = b2f(xc[(b*NN + i)*NF + d]);
          RM[(b*64 + d)*128 + i] = xv * rA[b*NN + i];
          RX[(b*64 + d)*128 + i] = 128.f * xv;
        } else {
          const u16* xcb = xc + b*NN*NF + (d - NF);
          const float* Ar = A + b*16384 + i*128;
          float sm = 0.f, sx = 0.f;
          for (int j = 0; j < 128; j++){
            float xj = b2f(xcb[j*NF]);
            sm += Ar[j]*xj; sx += xj;
          }
          RM[(b*64 + d)*128 + i] = sm;
          RX[(b*64 + d)*128 + i] = sx;
        }
      } else {
        const int j = t - 128;
        if (d < NF){
          const u16* xcb = xc + b*NN*NF + d;
          const float* Ac = A + b*16384 + j;
          float sm = 0.f, sx = 0.f;
          for (int i = 0; i < 128; i++){
            float xi = b2f(xcb[i*NF]);
            sm += Ac[i*128]*xi; sx += xi;
          }
          CM[(b*64 + d)*128 + j] = sm;
          CXv[(b*64 + d)*128 + j] = sx;
        } else {
          float xv = b2f(xc[(b*NN + j)*NF + (d - NF)]);
          CM[(b*64 + d)*128 + j] = xv * cA[b*NN + j];
          CXv[(b*64 + d)*128 + j] = 128.f * xv;
        }
      }
      return;
    }
    const u16* Xd = Xs + ((size_t)(b*ND + d) << 14);
    const float* Ab = A + b*NN*NN;
    float sm = 0.f, sx = 0.f;
    if (t < 128){
      const int i = t;
      #pragma unroll 2
      for (int j8 = 0; j8 < 16; j8++){
        short8 xv = *(const short8*)(Xd + i*128 + j8*8);
        float4 a0 = *(const float4*)(Ab + i*128 + j8*8);
        float4 a1 = *(const float4*)(Ab + i*128 + j8*8 + 4);
        float x0 = b2f((u16)xv[0]), x1 = b2f((u16)xv[1]), x2 = b2f((u16)xv[2]), x3 = b2f((u16)xv[3]);
        float x4 = b2f((u16)xv[4]), x5 = b2f((u16)xv[5]), x6 = b2f((u16)xv[6]), x7 = b2f((u16)xv[7]);
        sx += x0+x1+x2+x3+x4+x5+x6+x7;
        sm += x0*a0.x + x1*a0.y + x2*a0.z + x3*a0.w
            + x4*a1.x + x5*a1.y + x6*a1.z + x7*a1.w;
      }
      RM[(b*64 + d)*128 + i] = sm;
      RX[(b*64 + d)*128 + i] = sx;
    } else {
      const int j = t - 128;
      for (int i = 0; i < 128; i++){
        float xv = b2f(Xd[i*128 + j]);
        sx += xv;
        sm += xv * Ab[i*128 + j];
      }
      CM[(b*64 + d)*128 + j] = sm;
      CXv[(b*64 + d)*128 + j] = sx;
    }
    return;
  }

  const int w = t >> 6, lane = t & 63;
  const int col = lane & 15, quad = lane >> 4;
  const int ij0 = sub*64;

  __shared__ uint32_t lsb[4][32*SJ32];
  __shared__ float lsf[64*SJF];

  short8 wa[10][2];
  #pragma unroll
  for (int s = 0; s < 10; s++){
    const u16* wp = Wb + (size_t)((s*64 + w*16 + col)*64 + quad*8);
    wa[s][0] = *(const short8*)wp;
    wa[s][1] = *(const short8*)(wp + 32);
  }
  float a_s[4], t_s[4], rjv[4];
  #pragma unroll
  for (int sj = 0; sj < 4; sj++){
    int ij = ij0 + sj*16 + col;
    a_s[sj] = A[b*16384 + ij];
    t_s[sj] = AAt[b*16384 + ij];
    rjv[sj] = rA[b*128 + (ij & 127)];
  }
  const float riv = rA[b*128 + (ij0 >> 7)];

  uint32_t* ldsX = &lsb[0][0];
  {
    const int ep = t >> 3;
    const int s8 = (t & 7)*8;
    if (first){
      const int i = ij0 >> 7;
      const int j0 = (ij0 & 127) + s8;
      if (ep < 16){
        uint32_t p = *(const uint32_t*)(xc + (b*NN + i)*NF + 2*ep);
        #pragma unroll
        for (int k = 0; k < 8; k++) ldsX[(s8 + k)*SXE + ep] = p;
      } else {
        const int d0 = 2*ep - 32;
        #pragma unroll
        for (int k = 0; k < 8; k++)
          ldsX[(s8 + k)*SXE + ep] = *(const uint32_t*)(xc + (b*NN + j0 + k)*NF + d0);
      }
    } else {
      const u16* xp = Xs + ((size_t)(b*ND + 2*ep) << 14) + ij0 + s8;
      short8 r0 = *(const short8*)xp;
      short8 r1 = *(const short8*)(xp + 16384);
      #pragma unroll
      for (int k = 0; k < 8; k++)
        ldsX[(s8 + k)*SXE + ep] = ((uint32_t)(u16)r0[k]) | (((uint32_t)(u16)r1[k]) << 16);
    }
  }
  __syncthreads();
  short8 xb[4][2];
  #pragma unroll
  for (int sj = 0; sj < 4; sj++){
    #pragma unroll
    for (int h = 0; h < 2; h++){
      const uint32_t* p = &ldsX[(sj*16 + col)*SXE + quad*4 + h*16];
      uint2 u0 = *(const uint2*)p;
      uint2 u1 = *(const uint2*)(p + 2);
      union { uint32_t u[4]; short8 s; } cv;
      cv.u[0] = u0.x; cv.u[1] = u0.y; cv.u[2] = u1.x; cv.u[3] = u1.y;
      xb[sj][h] = cv.s;
    }
  }
  __syncthreads();

  #pragma unroll
  for (int g = 0; g < 5; g++){
    const int s0_tab[5]  = {0, 2, 4, 5, 6};
    const int nsl_tab[5] = {2, 2, 1, 1, 4};
    const int s0 = s0_tab[g], nsl = nsl_tab[g];
    #pragma unroll
    for (int sj = 0; sj < 4; sj++){
      f32x4 acc[4];
      #pragma unroll
      for (int s = 0; s < 4; s++) acc[s] = (f32x4){0.f,0.f,0.f,0.f};
      #pragma unroll
      for (int s = 0; s < 4; s++){
        if (s >= nsl) break;
        acc[s] = MFMA16(wa[s0+s][0], xb[sj][0], acc[s]);
        acc[s] = MFMA16(wa[s0+s][1], xb[sj][1], acc[s]);
      }
      if (g < 4){
        float v[4];
        #pragma unroll
        for (int r = 0; r < 4; r++){
          if (g == 2 || g == 3) v[r] = acc[0][r]*a_s[sj];
          else                  v[r] = acc[0][r]*a_s[sj] + acc[1][r];
        }
        uint32_t p0 = (uint32_t)f2b(v[0]) | ((uint32_t)f2b(v[1]) << 16);
        uint32_t p1 = (uint32_t)f2b(v[2]) | ((uint32_t)f2b(v[3]) << 16);
        int ep = w*8 + quad*2;
        lsb[g][ep*SJ32 + sj*16 + col] = p0;
        lsb[g][(ep + 1)*SJ32 + sj*16 + col] = p1;
      } else {
        #pragma unroll
        for (int r = 0; r < 4; r++){
          float v = acc[0][r]*t_s[sj] + acc[1][r]*riv + acc[2][r]*rjv[sj] + acc[3][r];
          lsf[(w*16 + quad*4 + r)*SJF + sj*16 + col] = v;
        }
      }
    }
  }
  __syncthreads();

  const int eo = t >> 2, seg = t & 3;
  const int ep = eo >> 1, sh = (eo & 1)*16;
  #pragma unroll
  for (int g = 0; g < 4; g++){
    const uint32_t* lp = &lsb[g][ep*SJ32 + seg*16];
    short8 v0, v1;
    #pragma unroll
    for (int k = 0; k < 8; k++){
      v0[k] = (short)((lp[k]   >> sh) & 0xffffu);
      v1[k] = (short)((lp[8+k] >> sh) & 0xffffu);
    }
    u16* U = (g==0)?Ua:(g==1)?Ub:(g==2)?Uc:Ud;
    u16* dst = U + ((size_t)(b*64 + eo) << 14) + ij0 + seg*16;
    *(short8*)dst = v0;
    *(short8*)(dst + 8) = v1;
  }
  {
    const float* fp = &lsf[eo*SJF + seg*16];
    float* dst = Yacc + ((size_t)(b*64 + eo) << 14) + ij0 + seg*16;
    #pragma unroll
    for (int q = 0; q < 4; q++)
      *(float4*)(dst + q*4) = make_float4(fp[q*4], fp[q*4+1], fp[q*4+2], fp[q*4+3]);
  }
}

#define SLT 68    // uint32 stride for transpose staging
#define SST 136   // uint32 stride for output staging (aliased onto uls)

// ---- fused tne, XCD-pair aligned: b = (bid&7)>>1, e = 2*(bid>>3)+(bid&1) ----
__global__ __launch_bounds__(512) void k_tne(const u16* __restrict__ ATb,
    const u16* __restrict__ Ua, const u16* __restrict__ Ub,
    const u16* __restrict__ Uc, const u16* __restrict__ Ud,
    const float* __restrict__ Yacc, const float* __restrict__ W,
    const float* __restrict__ RM, const float* __restrict__ CM,
    const float* __restrict__ RX, const float* __restrict__ CXv,
    const float* __restrict__ bias, u16* __restrict__ Xout, float* __restrict__ acc4,
    unsigned int* __restrict__ cnt, const u16* __restrict__ x16, void* __restrict__ outp,
    int last)
{
  const int bid = blockIdx.x;
  const int xcd = bid & 7;
  const int b = xcd >> 1;
  const int e = 2*(bid >> 3) + (xcd & 1);
  const int be = b*64 + e;
  const int t = threadIdx.x, wave = t >> 6, lane = t & 63;
  const int col = lane & 15, quad = lane >> 4;
  const int m0 = (wave >> 2)*64;        // 0 or 64
  const int n0 = (wave & 3)*32;         // 0,32,64,96

  __shared__ uint32_t uls[128*SLT];
  __shared__ uint32_t ubl[128*SLT];
  __shared__ float radd[128], cadd[128];
  __shared__ float red[8];
  __shared__ int flg, lastblk;

  if (t == 0){ flg = 0; lastblk = 0; }

  const u16* ua = Ua + ((size_t)be << 14);
  const u16* ub = Ub + ((size_t)be << 14);

  if (t < 128){
    int i = t; float s = 0.f;
    for (int d = 0; d < ND; d++){
      int v = (b*ND + d)*NN + i;
      s += W[(640 + d)*64 + e]*RM[v] + W[(704 + d)*64 + e]*CM[v]
         + W[(768 + d)*64 + e]*RX[v] + W[(832 + d)*64 + e]*CXv[v];
    }
    radd[i] = s;
  } else if (t < 256){
    int j = t - 128; float s = 0.f;
    for (int d = 0; d < ND; d++){
      int v = (b*ND + d)*NN + j;
      s += W[(896 + d)*64 + e]*RM[v] + W[(960 + d)*64 + e]*CM[v]
         + W[(1024 + d)*64 + e]*RX[v] + W[(1088 + d)*64 + e]*CXv[v];
    }
    cadd[j] = s;
  } else if (t < 384){
    const int tt = t - 256;
    const int kp = tt >> 1, p = tt & 1;
    #pragma unroll
    for (int it = 0; it < 8; it++){
      int mo = it*2 + p;
      short8 r0 = *(const short8*)(ua + (2*kp)*128 + mo*8);
      short8 r1 = *(const short8*)(ua + (2*kp + 1)*128 + mo*8);
      #pragma unroll
      for (int x = 0; x < 8; x++)
        uls[(mo*8 + x)*SLT + kp] = ((uint32_t)(u16)r0[x]) | (((uint32_t)(u16)r1[x]) << 16);
    }
  } else {
    const int tt = t - 384;
    const int kp = tt >> 1, p = tt & 1;
    #pragma unroll
    for (int it = 0; it < 8; it++){
      int no = it*2 + p;
      short8 r0 = *(const short8*)(ub + (2*kp)*128 + no*8);
      short8 r1 = *(const short8*)(ub + (2*kp + 1)*128 + no*8);
      #pragma unroll
      for (int x = 0; x < 8; x++)
        ubl[(no*8 + x)*SLT + kp] = ((uint32_t)(u16)r0[x]) | (((uint32_t)(u16)r1[x]) << 16);
    }
  }
  __syncthreads();

  f32x4 acc[4][2];
  #pragma unroll
  for (int mt = 0; mt < 4; mt++)
    #pragma unroll
    for (int nt = 0; nt < 2; nt++)
      acc[mt][nt] = (f32x4){0.f,0.f,0.f,0.f};

  const u16* at = ATb + ((size_t)b << 14);
  short8 at_n[4][2];
  #pragma unroll
  for (int kq = 0; kq < 4; kq++){
    int k0 = kq*32 + quad*8;
    at_n[kq][0] = *(const short8*)(at + (n0 + col)*128 + k0);
    at_n[kq][1] = *(const short8*)(at + (n0 + 16 + col)*128 + k0);
  }

  // f0: Ua^T · A
  #pragma unroll
  for (int kq = 0; kq < 4; kq++){
    int kd = kq*16 + quad*4;
    #pragma unroll
    for (int mt = 0; mt < 4; mt++){
      short8 af = *(const short8*)&uls[(m0 + mt*16 + col)*SLT + kd];
      acc[mt][0] = MFMA16(af, at_n[kq][0], acc[mt][0]);
      acc[mt][1] = MFMA16(af, at_n[kq][1], acc[mt][1]);
    }
  }
  // f2: Uc · A
  {
    const u16* uc = Uc + ((size_t)be << 14);
    #pragma unroll
    for (int kq = 0; kq < 4; kq++){
      int k0 = kq*32 + quad*8;
      #pragma unroll
      for (int mt = 0; mt < 4; mt++){
        short8 af = *(const short8*)(uc + (m0 + mt*16 + col)*128 + k0);
        acc[mt][0] = MFMA16(af, at_n[kq][0], acc[mt][0]);
        acc[mt][1] = MFMA16(af, at_n[kq][1], acc[mt][1]);
      }
    }
  }
  // f1 + f3 interleaved per kq: both consume the SAME at m-row fragments -> load once
  {
    const u16* ud = Ud + ((size_t)be << 14);
    #pragma unroll
    for (int kq = 0; kq < 4; kq++){
      int k0 = kq*32 + quad*8, kd = kq*16 + quad*4;
      short8 atm[4];
      #pragma unroll
      for (int mt = 0; mt < 4; mt++)
        atm[mt] = *(const short8*)(at + (m0 + mt*16 + col)*128 + k0);
      short8 bf0 = *(const short8*)&ubl[(n0 + col)*SLT + kd];
      short8 bf1 = *(const short8*)&ubl[(n0 + 16 + col)*SLT + kd];
      #pragma unroll
      for (int mt = 0; mt < 4; mt++){
        acc[mt][0] = MFMA16(atm[mt], bf0, acc[mt][0]);
        acc[mt][1] = MFMA16(atm[mt], bf1, acc[mt][1]);
      }
      short8 df0 = *(const short8*)(ud + (n0 + col)*128 + k0);
      short8 df1 = *(const short8*)(ud + (n0 + 16 + col)*128 + k0);
      #pragma unroll
      for (int mt = 0; mt < 4; mt++){
        acc[mt][0] = MFMA16(atm[mt], df0, acc[mt][0]);
        acc[mt][1] = MFMA16(atm[mt], df1, acc[mt][1]);
      }
    }
  }
  __syncthreads();

  uint32_t* stg = uls;
  const float bv = bias[e];
  const float* Y = Yacc + ((size_t)be << 14);
  if (!last){
    const int chalf = (n0 >> 6)*68 + (n0 & 32);
    #pragma unroll
    for (int mt = 0; mt < 4; mt++)
      #pragma unroll
      for (int nt = 0; nt < 2; nt++)
        #pragma unroll
        for (int rp = 0; rp < 2; rp++){
          uint32_t p = 0;
          #pragma unroll
          for (int h = 0; h < 2; h++){
            int r = rp*2 + h;
            int row = m0 + mt*16 + quad*4 + r;
            int cn = n0 + nt*16 + col;
            float v = acc[mt][nt][r] + Y[row*128 + cn] + radd[row] + cadd[cn] + bv;
            v = 1.f/(1.f + __expf(-v));
            p |= ((uint32_t)f2b(v)) << (16*h);
          }
          int ipair = ((m0 + mt*16 + quad*4) >> 1) + rp;
          stg[ipair*SST + chalf + nt*16 + col] = p;
        }
    __syncthreads();
    const int u = t & 255, half = t >> 8;
    const uint32_t* lp = &stg[(u >> 2)*SST + half*68 + (u & 1)*32];
    const int sh = ((u >> 1) & 1)*16;
    u16* dst = Xout + ((size_t)be << 14) + (size_t)(u >> 1)*128 + half*64 + (u & 1)*32;
    #pragma unroll
    for (int q2 = 0; q2 < 4; q2++){
      short8 v;
      #pragma unroll
      for (int k = 0; k < 8; k++) v[k] = (short)((lp[q2*8 + k] >> sh) & 0xffffu);
      *(short8*)(dst + q2*8) = v;
    }
  } else {
    float loc = 0.f;
    #pragma unroll
    for (int mt = 0; mt < 4; mt++)
      #pragma unroll
      for (int nt = 0; nt < 2; nt++)
        #pragma unroll
        for (int r = 0; r < 4; r++){
          int row = m0 + mt*16 + quad*4 + r;
          int cn = n0 + nt*16 + col;
          loc += acc[mt][nt][r] + Y[row*128 + cn] + radd[row] + cadd[cn] + bv;
        }
    for (int off = 32; off > 0; off >>= 1) loc += __shfl_down(loc, off, 64);
    if (lane == 0) red[wave] = loc;
    __syncthreads();
    if (t == 0){
      float s = 0.f;
      #pragma unroll
      for (int wv = 0; wv < 8; wv++) s += red[wv];
      atomicAdd(&acc4[b], s);
      __threadfence();
      unsigned int old = atomicAdd(cnt, 1u);
      if (old == 255u) lastblk = 1;
    }
    __syncthreads();
    if (lastblk){
      if (((x16[t] >> 7) & 0xFF) >= 0x90) flg = 1;
      __syncthreads();
      if (t < NB){
        float v = atomicAdd(&acc4[t], 0.f) * (1.0f/1048576.0f);
        if (flg) ((float*)outp)[t] = v;
        else     ((u16*)outp)[t] = f2b(v);
      }
    }
  }
}

extern "C" void kernel_launch(void* const* d_in, const int* in_sizes, int n_in,
                              void* d_out, int out_size, void* d_ws, size_t ws_size,
                              hipStream_t stream)
{
  const void* x   = d_in[0];
  const void* ew  = d_in[1];
  const void* c1  = d_in[2];
  const void* b1  = d_in[3];
  const void* c2  = d_in[4];
  const void* b2  = d_in[5];
  const int* ei  = (const int*)d_in[6];
  const int* bat = (const int*)d_in[7];
  const int E = in_sizes[1];

  char* wsb = (char*)d_ws;
  float* A    = (float*)(wsb + OFF_A);
  float* acc4 = (float*)(wsb + OFF_ACC);
  unsigned int* cnt = (unsigned int*)(wsb + OFF_ACC + 32);
  float* AAt  = (float*)(wsb + OFF_AAT);
  float* rA   = (float*)(wsb + OFF_RA);
  float* W    = (float*)(wsb + OFF_W);
  float* RM   = (float*)(wsb + OFF_RM);
  float* CM   = (float*)(wsb + OFF_CM);
  float* RX   = (float*)(wsb + OFF_RX);
  float* CXv  = (float*)(wsb + OFF_CX);
  float* bfv  = (float*)(wsb + OFF_BF);
  u16* ATb = (u16*)(wsb + OFF_ATB);
  u16* Wb  = (u16*)(wsb + OFF_WB);
  u16* X2  = (u16*)(wsb + OFF_X2);
  u16* xc  = (u16*)(wsb + OFF_XC);
  float* cA = (float*)(wsb + OFF_CA);
  u16* Ua  = (u16*)(wsb + OFF_UA);
  u16* Ub  = (u16*)(wsb + OFF_UB);
  u16* Uc  = (u16*)(wsb + OFF_UC);
  u16* Ud  = (u16*)(wsb + OFF_UD);
  float* Yacc = (float*)(wsb + OFF_YACC);

  hipMemsetAsync(wsb, 0, OFF_AAT, stream);   // zero A + acc4 + cnt

  k_setup<<<dim3(616), dim3(256), 0, stream>>>(ei, bat, ew, A, E, x, xc,
                                               c1, c2, b1, b2, W, Wb, bfv);
  k_prepA<<<dim3(136), dim3(256), 0, stream>>>(A, AAt, ATb, rA, cA);

  for (int L = 0; L < 2; L++){
    const float* Wl = W + (size_t)L*1152*64;
    const u16*  Wbl = Wb + (size_t)L*10*64*64;
    k_mixrow<<<dim3(1280), dim3(256), 0, stream>>>(X2, A, AAt, rA, cA, xc, Wbl,
                                                   Ua, Ub, Uc, Ud, Yacc, RM, CM, RX, CXv,
                                                   L == 0 ? 1 : 0);
    k_tne<<<dim3(256), dim3(512), 0, stream>>>(ATb, Ua, Ub, Uc, Ud, Yacc, Wl,
                                               RM, CM, RX, CXv, bfv + L*64, X2, acc4,
                                               cnt, (const u16*)x, d_out, L);
  }
}

// Round 8
// 195.330 us; speedup vs baseline: 1.2251x; 1.2251x over previous
//
#include <hip/hip_runtime.h>
#include <stdint.h>

typedef unsigned short u16;
using short8 = __attribute__((ext_vector_type(8))) short;
using f32x4  = __attribute__((ext_vector_type(4))) float;

#define NB 4
#define NN 128
#define NF 32
#define ND 64

// ---- workspace byte offsets ----
#define OFF_A     0u
#define OFF_ACC   262144u
#define OFF_AAT   262400u
#define OFF_RA    524544u
#define OFF_W     526592u
#define OFF_RM    1116416u
#define OFF_CM    1247488u
#define OFF_RX    1378560u
#define OFF_CX    1509632u
#define OFF_BF    1640960u
#define OFF_ATB   1641472u
#define OFF_WB    1772544u
#define OFF_X2    1936384u
#define OFF_XC    10324992u
#define OFF_CA    10357760u
#define OFF_UA    18713600u
#define OFF_UB    27102208u
#define OFF_UC    35490816u
#define OFF_UD    43879424u
#define OFF_YACC  52268032u

__device__ __forceinline__ float b2f(u16 v){
  union { uint32_t u; float f; } x; x.u = ((uint32_t)v) << 16; return x.f;
}
__device__ __forceinline__ u16 f2b(float f){
  union { uint32_t u; float f2; } x; x.f2 = f;
  uint32_t u = x.u;
  return (u16)((u + 0x7FFFu + ((u >> 16) & 1u)) >> 16);
}

#define MFMA16(a,b,c) __builtin_amdgcn_mfma_f32_16x16x32_bf16((a),(b),(c),0,0,0)

__device__ __constant__ signed char dR1[18] = {0,9,1,10,2,3,4,13,14,19,5,7,15,18,6,8,16,17};
__device__ __constant__ signed char dR2[18] = {-1,11,-1,12,-1,-1,-1,-1,-1,-1,-1,-1,-1,-1,-1,-1,-1,-1};

// ---- fused setup: scatter+bias | xc (bf16 copy of x) | build W ; inline dtype detect ----
__global__ void k_setup(const int* __restrict__ ei, const int* __restrict__ bat,
                        const void* __restrict__ ews, float* __restrict__ A, int E,
                        const void* __restrict__ xs, u16* __restrict__ xc,
                        const void* __restrict__ c1s, const void* __restrict__ c2s,
                        const void* __restrict__ b1s, const void* __restrict__ b2s,
                        float* __restrict__ W, u16* __restrict__ Wb,
                        float* __restrict__ bfv)
{
  __shared__ int flg;
  const u16* x16 = (const u16*)xs;
  if (threadIdx.x == 0) flg = 0;
  __syncthreads();
  int hit = 0;
  for (int k = threadIdx.x; k < 1024; k += 256){
    u16 u = x16[k];
    if (((u >> 7) & 0xFF) >= 0x90) hit = 1;
  }
  if (hit) flg = 1;
  __syncthreads();
  const int isf = flg;

  const int bx = blockIdx.x;
  if (bx < 32){
    if (bx == 0 && threadIdx.x < 128){
      int tt = threadIdx.x;
      const void* bsrc = (tt < 64) ? b1s : b2s;
      int idx = tt & 63;
      bfv[tt] = isf ? ((const float*)bsrc)[idx] : b2f(((const u16*)bsrc)[idx]);
    }
    for (int t = bx*256 + threadIdx.x; t < E; t += 32*256){
      int s = ei[t], dnode = ei[E + t];
      int g = bat[s];
      int r = s - g*NN, c = dnode - g*NN;
      float wv = isf ? ((const float*)ews)[t] : b2f(((const u16*)ews)[t]);
      atomicAdd(&A[(g*NN + r)*NN + c], wv);
    }
  } else if (bx < 40){
    int idx8 = ((bx - 32)*256 + threadIdx.x)*8;
    if (!isf){
      *(short8*)(xc + idx8) = *(const short8*)(x16 + idx8);
    } else {
      const float* xfp = (const float*)xs;
      short8 v;
      #pragma unroll
      for (int k = 0; k < 8; k++) v[k] = (short)f2b(xfp[idx8 + k]);
      *(short8*)(xc + idx8) = v;
    }
  } else {
    int gl = (bx - 40)*256 + threadIdx.x;
    if (gl >= 2*1152*64) return;
    int L = gl / (1152*64);
    int rem = gl - L*1152*64;
    int row = rem >> 6, e = rem & 63;
    int slot = row >> 6, d = row & 63;
    const void* cr = L ? c2s : c1s;
    int base = (d*64 + e)*20;
    int i1 = base + dR1[slot];
    float v = isf ? ((const float*)cr)[i1] : b2f(((const u16*)cr)[i1]);
    if (dR2[slot] >= 0){
      int i2 = base + dR2[slot];
      v += isf ? ((const float*)cr)[i2] : b2f(((const u16*)cr)[i2]);
    }
    float scale = (slot == 9) ? 1.0f : (1.0f/128.0f);
    v *= scale;
    W[gl] = v;
    if (slot < 10)
      Wb[(((size_t)L*10 + slot)*64 + e)*64 + d] = f2b(v);
  }
}

// ---- fused A-processing: iq<32 = AAt (4 rows each, float4 K) | iq==32 = ATb + rA + cA ----
__global__ __launch_bounds__(256) void k_prepA(const float* __restrict__ A, float* __restrict__ AAt,
                                               u16* __restrict__ ATb, float* __restrict__ rA,
                                               float* __restrict__ cA){
  const int iq = blockIdx.x, b = blockIdx.y;
  const int t = threadIdx.x;
  if (iq < 32){
    int j = t & 127, ih = t >> 7;
    int i0 = iq*4 + ih, i1 = i0 + 2;
    const float* Ab = A + b*NN*NN;
    float acc0 = 0.f, acc1 = 0.f;
    #pragma unroll 4
    for (int k = 0; k < 128; k += 4){
      float4 aj = *(const float4*)(Ab + j*128 + k);
      float4 a0 = *(const float4*)(Ab + i0*128 + k);
      float4 a1 = *(const float4*)(Ab + i1*128 + k);
      acc0 += a0.x*aj.x + a0.y*aj.y + a0.z*aj.z + a0.w*aj.w;
      acc1 += a1.x*aj.x + a1.y*aj.y + a1.z*aj.z + a1.w*aj.w;
    }
    AAt[(b*NN + i0)*NN + j] = acc0;
    AAt[(b*NN + i1)*NN + j] = acc1;
  } else {
    __shared__ float lds[128][129];
    for (int l = 0; l < 64; l++){
      int idx = l*256 + t;
      lds[idx >> 7][idx & 127] = A[b*16384 + idx];
    }
    __syncthreads();
    for (int l = 0; l < 64; l++){
      int idx = l*256 + t;
      int r = idx >> 7, c = idx & 127;
      ATb[b*16384 + idx] = f2b(lds[c][r]);
    }
    if (t < 128){
      float s = 0.f;
      for (int j = 0; j < 128; j++) s += lds[t][j];
      rA[b*NN + t] = s;
    } else {
      int c = t - 128;
      float s = 0.f;
      for (int j = 0; j < 128; j++) s += lds[j][c];
      cA[b*NN + c] = s;
    }
  }
}

#define SJ32 70   // u32 stride, bf16-pair staging
#define SJF  67   // fp32 stride, Yacc staging
#define SXE  34   // u32 stride, X pair-packed transpose staging

// ---- fused: mix (bx<256) | rowcol (bx>=256; L0 closed forms, L1 general) ----
__global__ __launch_bounds__(256) void k_mixrow(const u16* __restrict__ Xs, const float* __restrict__ A,
    const float* __restrict__ AAt, const float* __restrict__ rA, const float* __restrict__ cA,
    const u16* __restrict__ xc, const u16* __restrict__ Wb,
    u16* __restrict__ Ua, u16* __restrict__ Ub, u16* __restrict__ Uc, u16* __restrict__ Ud,
    float* __restrict__ Yacc,
    float* __restrict__ RM, float* __restrict__ CM,
    float* __restrict__ RX, float* __restrict__ CXv, int first)
{
  const int b = blockIdx.y;
  const int t = threadIdx.x;

  if (blockIdx.x >= 256){
    const int d = blockIdx.x - 256;          // 0..63
    if (first){
      if (t < 128){
        const int i = t;
        if (d < NF){
          float xv = b2f(xc[(b*NN + i)*NF + d]);
          RM[(b*64 + d)*128 + i] = xv * rA[b*NN + i];
          RX[(b*64 + d)*128 + i] = 128.f * xv;
        } else {
          const u16* xcb = xc + b*NN*NF + (d - NF);
          const float* Ar = A + b*16384 + i*128;
          float sm = 0.f, sx = 0.f;
          for (int j = 0; j < 128; j++){
            float xj = b2f(xcb[j*NF]);
            sm += Ar[j]*xj; sx += xj;
          }
          RM[(b*64 + d)*128 + i] = sm;
          RX[(b*64 + d)*128 + i] = sx;
        }
      } else {
        const int j = t - 128;
        if (d < NF){
          const u16* xcb = xc + b*NN*NF + d;
          const float* Ac = A + b*16384 + j;
          float sm = 0.f, sx = 0.f;
          for (int i = 0; i < 128; i++){
            float xi = b2f(xcb[i*NF]);
            sm += Ac[i*128]*xi; sx += xi;
          }
          CM[(b*64 + d)*128 + j] = sm;
          CXv[(b*64 + d)*128 + j] = sx;
        } else {
          float xv = b2f(xc[(b*NN + j)*NF + (d - NF)]);
          CM[(b*64 + d)*128 + j] = xv * cA[b*NN + j];
          CXv[(b*64 + d)*128 + j] = 128.f * xv;
        }
      }
      return;
    }
    const u16* Xd = Xs + ((size_t)(b*ND + d) << 14);
    const float* Ab = A + b*NN*NN;
    float sm = 0.f, sx = 0.f;
    if (t < 128){
      const int i = t;
      #pragma unroll 2
      for (int j8 = 0; j8 < 16; j8++){
        short8 xv = *(const short8*)(Xd + i*128 + j8*8);
        float4 a0 = *(const float4*)(Ab + i*128 + j8*8);
        float4 a1 = *(const float4*)(Ab + i*128 + j8*8 + 4);
        float x0 = b2f((u16)xv[0]), x1 = b2f((u16)xv[1]), x2 = b2f((u16)xv[2]), x3 = b2f((u16)xv[3]);
        float x4 = b2f((u16)xv[4]), x5 = b2f((u16)xv[5]), x6 = b2f((u16)xv[6]), x7 = b2f((u16)xv[7]);
        sx += x0+x1+x2+x3+x4+x5+x6+x7;
        sm += x0*a0.x + x1*a0.y + x2*a0.z + x3*a0.w
            + x4*a1.x + x5*a1.y + x6*a1.z + x7*a1.w;
      }
      RM[(b*64 + d)*128 + i] = sm;
      RX[(b*64 + d)*128 + i] = sx;
    } else {
      const int j = t - 128;
      for (int i = 0; i < 128; i++){
        float xv = b2f(Xd[i*128 + j]);
        sx += xv;
        sm += xv * Ab[i*128 + j];
      }
      CM[(b*64 + d)*128 + j] = sm;
      CXv[(b*64 + d)*128 + j] = sx;
    }
    return;
  }

  const int w = t >> 6, lane = t & 63;
  const int col = lane & 15, quad = lane >> 4;
  const int ij0 = blockIdx.x*64;

  __shared__ uint32_t lsb[4][32*SJ32];
  __shared__ float lsf[64*SJF];

  short8 wa[10][2];
  #pragma unroll
  for (int s = 0; s < 10; s++){
    const u16* wp = Wb + (size_t)((s*64 + w*16 + col)*64 + quad*8);
    wa[s][0] = *(const short8*)wp;
    wa[s][1] = *(const short8*)(wp + 32);
  }
  float a_s[4], t_s[4], rjv[4];
  #pragma unroll
  for (int sj = 0; sj < 4; sj++){
    int ij = ij0 + sj*16 + col;
    a_s[sj] = A[b*16384 + ij];
    t_s[sj] = AAt[b*16384 + ij];
    rjv[sj] = rA[b*128 + (ij & 127)];
  }
  const float riv = rA[b*128 + (ij0 >> 7)];

  uint32_t* ldsX = &lsb[0][0];
  {
    const int ep = t >> 3;
    const int s8 = (t & 7)*8;
    if (first){
      const int i = ij0 >> 7;
      const int j0 = (ij0 & 127) + s8;
      if (ep < 16){
        uint32_t p = *(const uint32_t*)(xc + (b*NN + i)*NF + 2*ep);
        #pragma unroll
        for (int k = 0; k < 8; k++) ldsX[(s8 + k)*SXE + ep] = p;
      } else {
        const int d0 = 2*ep - 32;
        #pragma unroll
        for (int k = 0; k < 8; k++)
          ldsX[(s8 + k)*SXE + ep] = *(const uint32_t*)(xc + (b*NN + j0 + k)*NF + d0);
      }
    } else {
      const u16* xp = Xs + ((size_t)(b*ND + 2*ep) << 14) + ij0 + s8;
      short8 r0 = *(const short8*)xp;
      short8 r1 = *(const short8*)(xp + 16384);
      #pragma unroll
      for (int k = 0; k < 8; k++)
        ldsX[(s8 + k)*SXE + ep] = ((uint32_t)(u16)r0[k]) | (((uint32_t)(u16)r1[k]) << 16);
    }
  }
  __syncthreads();
  short8 xb[4][2];
  #pragma unroll
  for (int sj = 0; sj < 4; sj++){
    #pragma unroll
    for (int h = 0; h < 2; h++){
      const uint32_t* p = &ldsX[(sj*16 + col)*SXE + quad*4 + h*16];
      uint2 u0 = *(const uint2*)p;
      uint2 u1 = *(const uint2*)(p + 2);
      union { uint32_t u[4]; short8 s; } cv;
      cv.u[0] = u0.x; cv.u[1] = u0.y; cv.u[2] = u1.x; cv.u[3] = u1.y;
      xb[sj][h] = cv.s;
    }
  }
  __syncthreads();

  #pragma unroll
  for (int g = 0; g < 5; g++){
    const int s0_tab[5]  = {0, 2, 4, 5, 6};
    const int nsl_tab[5] = {2, 2, 1, 1, 4};
    const int s0 = s0_tab[g], nsl = nsl_tab[g];
    #pragma unroll
    for (int sj = 0; sj < 4; sj++){
      f32x4 acc[4];
      #pragma unroll
      for (int s = 0; s < 4; s++) acc[s] = (f32x4){0.f,0.f,0.f,0.f};
      #pragma unroll
      for (int s = 0; s < 4; s++){
        if (s >= nsl) break;
        acc[s] = MFMA16(wa[s0+s][0], xb[sj][0], acc[s]);
        acc[s] = MFMA16(wa[s0+s][1], xb[sj][1], acc[s]);
      }
      if (g < 4){
        float v[4];
        #pragma unroll
        for (int r = 0; r < 4; r++){
          if (g == 2 || g == 3) v[r] = acc[0][r]*a_s[sj];
          else                  v[r] = acc[0][r]*a_s[sj] + acc[1][r];
        }
        uint32_t p0 = (uint32_t)f2b(v[0]) | ((uint32_t)f2b(v[1]) << 16);
        uint32_t p1 = (uint32_t)f2b(v[2]) | ((uint32_t)f2b(v[3]) << 16);
        int ep = w*8 + quad*2;
        lsb[g][ep*SJ32 + sj*16 + col] = p0;
        lsb[g][(ep + 1)*SJ32 + sj*16 + col] = p1;
      } else {
        #pragma unroll
        for (int r = 0; r < 4; r++){
          float v = acc[0][r]*t_s[sj] + acc[1][r]*riv + acc[2][r]*rjv[sj] + acc[3][r];
          lsf[(w*16 + quad*4 + r)*SJF + sj*16 + col] = v;
        }
      }
    }
  }
  __syncthreads();

  const int eo = t >> 2, seg = t & 3;
  const int ep = eo >> 1, sh = (eo & 1)*16;
  #pragma unroll
  for (int g = 0; g < 4; g++){
    const uint32_t* lp = &lsb[g][ep*SJ32 + seg*16];
    short8 v0, v1;
    #pragma unroll
    for (int k = 0; k < 8; k++){
      v0[k] = (short)((lp[k]   >> sh) & 0xffffu);
      v1[k] = (short)((lp[8+k] >> sh) & 0xffffu);
    }
    u16* U = (g==0)?Ua:(g==1)?Ub:(g==2)?Uc:Ud;
    u16* dst = U + ((size_t)(b*64 + eo) << 14) + ij0 + seg*16;
    *(short8*)dst = v0;
    *(short8*)(dst + 8) = v1;
  }
  {
    const float* fp = &lsf[eo*SJF + seg*16];
    float* dst = Yacc + ((size_t)(b*64 + eo) << 14) + ij0 + seg*16;
    #pragma unroll
    for (int q = 0; q < 4; q++)
      *(float4*)(dst + q*4) = make_float4(fp[q*4], fp[q*4+1], fp[q*4+2], fp[q*4+3]);
  }
}

#define SLT 68    // uint32 stride for transpose staging
#define SST 136   // uint32 stride for output staging (aliased onto uls)

// ---- fused: 512-thread full 128x128 tile; preamble ∥ staging on disjoint waves;
//      launch_bounds(512,4): LDS caps at 2 blocks/CU anyway -> give compiler 128 VGPRs
//      for deeper load-ahead in the latency-bound MFMA section.
//      at_n loads hoisted above the barrier (no LDS dependency). ----
__global__ __launch_bounds__(512, 4) void k_tne(const u16* __restrict__ ATb,
    const u16* __restrict__ Ua, const u16* __restrict__ Ub,
    const u16* __restrict__ Uc, const u16* __restrict__ Ud,
    const float* __restrict__ Yacc, const float* __restrict__ W,
    const float* __restrict__ RM, const float* __restrict__ CM,
    const float* __restrict__ RX, const float* __restrict__ CXv,
    const float* __restrict__ bias, u16* __restrict__ Xout, float* __restrict__ acc4,
    unsigned int* __restrict__ cnt, const u16* __restrict__ x16, void* __restrict__ outp,
    int last)
{
  const int be = blockIdx.x;
  const int b = be >> 6, e = be & 63;
  const int t = threadIdx.x, wave = t >> 6, lane = t & 63;
  const int col = lane & 15, quad = lane >> 4;
  const int m0 = (wave >> 2)*64;        // 0 or 64
  const int n0 = (wave & 3)*32;         // 0,32,64,96

  __shared__ uint32_t uls[128*SLT];
  __shared__ uint32_t ubl[128*SLT];
  __shared__ float radd[128], cadd[128];
  __shared__ float red[8];
  __shared__ int flg, lastblk;

  if (t == 0){ flg = 0; lastblk = 0; }

  const u16* ua = Ua + ((size_t)be << 14);
  const u16* ub = Ub + ((size_t)be << 14);
  const u16* at = ATb + ((size_t)b << 14);

  // hoisted: B-operand fragments from ATb (no dependency on LDS staging)
  short8 at_n[4][2];
  #pragma unroll
  for (int kq = 0; kq < 4; kq++){
    int k0 = kq*32 + quad*8;
    at_n[kq][0] = *(const short8*)(at + (n0 + col)*128 + k0);
    at_n[kq][1] = *(const short8*)(at + (n0 + 16 + col)*128 + k0);
  }

  if (t < 128){
    int i = t; float s = 0.f;
    for (int d = 0; d < ND; d++){
      int v = (b*ND + d)*NN + i;
      s += W[(640 + d)*64 + e]*RM[v] + W[(704 + d)*64 + e]*CM[v]
         + W[(768 + d)*64 + e]*RX[v] + W[(832 + d)*64 + e]*CXv[v];
    }
    radd[i] = s;
  } else if (t < 256){
    int j = t - 128; float s = 0.f;
    for (int d = 0; d < ND; d++){
      int v = (b*ND + d)*NN + j;
      s += W[(896 + d)*64 + e]*RM[v] + W[(960 + d)*64 + e]*CM[v]
         + W[(1024 + d)*64 + e]*RX[v] + W[(1088 + d)*64 + e]*CXv[v];
    }
    cadd[j] = s;
  } else if (t < 384){
    const int tt = t - 256;
    const int kp = tt >> 1, p = tt & 1;
    #pragma unroll
    for (int it = 0; it < 8; it++){
      int mo = it*2 + p;
      short8 r0 = *(const short8*)(ua + (2*kp)*128 + mo*8);
      short8 r1 = *(const short8*)(ua + (2*kp + 1)*128 + mo*8);
      #pragma unroll
      for (int x = 0; x < 8; x++)
        uls[(mo*8 + x)*SLT + kp] = ((uint32_t)(u16)r0[x]) | (((uint32_t)(u16)r1[x]) << 16);
    }
  } else {
    const int tt = t - 384;
    const int kp = tt >> 1, p = tt & 1;
    #pragma unroll
    for (int it = 0; it < 8; it++){
      int no = it*2 + p;
      short8 r0 = *(const short8*)(ub + (2*kp)*128 + no*8);
      short8 r1 = *(const short8*)(ub + (2*kp + 1)*128 + no*8);
      #pragma unroll
      for (int x = 0; x < 8; x++)
        ubl[(no*8 + x)*SLT + kp] = ((uint32_t)(u16)r0[x]) | (((uint32_t)(u16)r1[x]) << 16);
    }
  }
  __syncthreads();

  f32x4 acc[4][2];
  #pragma unroll
  for (int mt = 0; mt < 4; mt++)
    #pragma unroll
    for (int nt = 0; nt < 2; nt++)
      acc[mt][nt] = (f32x4){0.f,0.f,0.f,0.f};

  // f0: Ua^T · A
  #pragma unroll
  for (int kq = 0; kq < 4; kq++){
    int kd = kq*16 + quad*4;
    #pragma unroll
    for (int mt = 0; mt < 4; mt++){
      short8 af = *(const short8*)&uls[(m0 + mt*16 + col)*SLT + kd];
      acc[mt][0] = MFMA16(af, at_n[kq][0], acc[mt][0]);
      acc[mt][1] = MFMA16(af, at_n[kq][1], acc[mt][1]);
    }
  }
  // f2: Uc · A
  {
    const u16* uc = Uc + ((size_t)be << 14);
    #pragma unroll
    for (int kq = 0; kq < 4; kq++){
      int k0 = kq*32 + quad*8;
      #pragma unroll
      for (int mt = 0; mt < 4; mt++){
        short8 af = *(const short8*)(uc + (m0 + mt*16 + col)*128 + k0);
        acc[mt][0] = MFMA16(af, at_n[kq][0], acc[mt][0]);
        acc[mt][1] = MFMA16(af, at_n[kq][1], acc[mt][1]);
      }
    }
  }
  // f1 + f3 interleaved per kq: both consume the SAME at m-row fragments -> load once
  {
    const u16* ud = Ud + ((size_t)be << 14);
    #pragma unroll
    for (int kq = 0; kq < 4; kq++){
      int k0 = kq*32 + quad*8, kd = kq*16 + quad*4;
      short8 atm[4];
      #pragma unroll
      for (int mt = 0; mt < 4; mt++)
        atm[mt] = *(const short8*)(at + (m0 + mt*16 + col)*128 + k0);
      short8 bf0 = *(const short8*)&ubl[(n0 + col)*SLT + kd];
      short8 bf1 = *(const short8*)&ubl[(n0 + 16 + col)*SLT + kd];
      #pragma unroll
      for (int mt = 0; mt < 4; mt++){
        acc[mt][0] = MFMA16(atm[mt], bf0, acc[mt][0]);
        acc[mt][1] = MFMA16(atm[mt], bf1, acc[mt][1]);
      }
      short8 df0 = *(const short8*)(ud + (n0 + col)*128 + k0);
      short8 df1 = *(const short8*)(ud + (n0 + 16 + col)*128 + k0);
      #pragma unroll
      for (int mt = 0; mt < 4; mt++){
        acc[mt][0] = MFMA16(atm[mt], df0, acc[mt][0]);
        acc[mt][1] = MFMA16(atm[mt], df1, acc[mt][1]);
      }
    }
  }
  __syncthreads();

  uint32_t* stg = uls;
  const float bv = bias[e];
  const float* Y = Yacc + ((size_t)be << 14);
  if (!last){
    const int chalf = (n0 >> 6)*68 + (n0 & 32);
    #pragma unroll
    for (int mt = 0; mt < 4; mt++)
      #pragma unroll
      for (int nt = 0; nt < 2; nt++)
        #pragma unroll
        for (int rp = 0; rp < 2; rp++){
          uint32_t p = 0;
          #pragma unroll
          for (int h = 0; h < 2; h++){
            int r = rp*2 + h;
            int row = m0 + mt*16 + quad*4 + r;
            int cn = n0 + nt*16 + col;
            float v = acc[mt][nt][r] + Y[row*128 + cn] + radd[row] + cadd[cn] + bv;
            v = 1.f/(1.f + __expf(-v));
            p |= ((uint32_t)f2b(v)) << (16*h);
          }
          int ipair = ((m0 + mt*16 + quad*4) >> 1) + rp;
          stg[ipair*SST + chalf + nt*16 + col] = p;
        }
    __syncthreads();
    const int u = t & 255, half = t >> 8;
    const uint32_t* lp = &stg[(u >> 2)*SST + half*68 + (u & 1)*32];
    const int sh = ((u >> 1) & 1)*16;
    u16* dst = Xout + ((size_t)be << 14) + (size_t)(u >> 1)*128 + half*64 + (u & 1)*32;
    #pragma unroll
    for (int q2 = 0; q2 < 4; q2++){
      short8 v;
      #pragma unroll
      for (int k = 0; k < 8; k++) v[k] = (short)((lp[q2*8 + k] >> sh) & 0xffffu);
      *(short8*)(dst + q2*8) = v;
    }
  } else {
    float loc = 0.f;
    #pragma unroll
    for (int mt = 0; mt < 4; mt++)
      #pragma unroll
      for (int nt = 0; nt < 2; nt++)
        #pragma unroll
        for (int r = 0; r < 4; r++){
          int row = m0 + mt*16 + quad*4 + r;
          int cn = n0 + nt*16 + col;
          loc += acc[mt][nt][r] + Y[row*128 + cn] + radd[row] + cadd[cn] + bv;
        }
    for (int off = 32; off > 0; off >>= 1) loc += __shfl_down(loc, off, 64);
    if (lane == 0) red[wave] = loc;
    __syncthreads();
    if (t == 0){
      float s = 0.f;
      #pragma unroll
      for (int wv = 0; wv < 8; wv++) s += red[wv];
      atomicAdd(&acc4[b], s);
      __threadfence();
      unsigned int old = atomicAdd(cnt, 1u);
      if (old == 255u) lastblk = 1;
    }
    __syncthreads();
    if (lastblk){
      if (((x16[t] >> 7) & 0xFF) >= 0x90) flg = 1;
      __syncthreads();
      if (t < NB){
        float v = atomicAdd(&acc4[t], 0.f) * (1.0f/1048576.0f);
        if (flg) ((float*)outp)[t] = v;
        else     ((u16*)outp)[t] = f2b(v);
      }
    }
  }
}

extern "C" void kernel_launch(void* const* d_in, const int* in_sizes, int n_in,
                              void* d_out, int out_size, void* d_ws, size_t ws_size,
                              hipStream_t stream)
{
  const void* x   = d_in[0];
  const void* ew  = d_in[1];
  const void* c1  = d_in[2];
  const void* b1  = d_in[3];
  const void* c2  = d_in[4];
  const void* b2  = d_in[5];
  const int* ei  = (const int*)d_in[6];
  const int* bat = (const int*)d_in[7];
  const int E = in_sizes[1];

  char* wsb = (char*)d_ws;
  float* A    = (float*)(wsb + OFF_A);
  float* acc4 = (float*)(wsb + OFF_ACC);
  unsigned int* cnt = (unsigned int*)(wsb + OFF_ACC + 32);
  float* AAt  = (float*)(wsb + OFF_AAT);
  float* rA   = (float*)(wsb + OFF_RA);
  float* W    = (float*)(wsb + OFF_W);
  float* RM   = (float*)(wsb + OFF_RM);
  float* CM   = (float*)(wsb + OFF_CM);
  float* RX   = (float*)(wsb + OFF_RX);
  float* CXv  = (float*)(wsb + OFF_CX);
  float* bfv  = (float*)(wsb + OFF_BF);
  u16* ATb = (u16*)(wsb + OFF_ATB);
  u16* Wb  = (u16*)(wsb + OFF_WB);
  u16* X2  = (u16*)(wsb + OFF_X2);
  u16* xc  = (u16*)(wsb + OFF_XC);
  float* cA = (float*)(wsb + OFF_CA);
  u16* Ua  = (u16*)(wsb + OFF_UA);
  u16* Ub  = (u16*)(wsb + OFF_UB);
  u16* Uc  = (u16*)(wsb + OFF_UC);
  u16* Ud  = (u16*)(wsb + OFF_UD);
  float* Yacc = (float*)(wsb + OFF_YACC);

  hipMemsetAsync(wsb, 0, OFF_AAT, stream);   // zero A + acc4 + cnt

  k_setup<<<dim3(616), dim3(256), 0, stream>>>(ei, bat, ew, A, E, x, xc,
                                               c1, c2, b1, b2, W, Wb, bfv);
  k_prepA<<<dim3(33, NB), dim3(256), 0, stream>>>(A, AAt, ATb, rA, cA);

  for (int L = 0; L < 2; L++){
    const float* Wl = W + (size_t)L*1152*64;
    const u16*  Wbl = Wb + (size_t)L*10*64*64;
    k_mixrow<<<dim3(320, NB), dim3(256), 0, stream>>>(X2, A, AAt, rA, cA, xc, Wbl,
                                                      Ua, Ub, Uc, Ud, Yacc, RM, CM, RX, CXv,
                                                      L == 0 ? 1 : 0);
    k_tne<<<dim3(256), dim3(512), 0, stream>>>(ATb, Ua, Ub, Uc, Ud, Yacc, Wl,
                                               RM, CM, RX, CXv, bfv + L*64, X2, acc4,
                                               cnt, (const u16*)x, d_out, L);
  }
}